// Round 1
// baseline (1616.433 us; speedup 1.0000x reference)
//
#include <hip/hip_runtime.h>
#include <cstdint>
#include <cstddef>

#define D_DIM 2048
#define F_DIM 8192
#define M_DIM 8192   // 4 * 2048 tokens
#define SCALING 2.0f
#define GAMMA 0.1f
#define LDS_PITCH 40  // 32 bf16 + 8 pad -> 80B row stride (16B aligned, even bank spread)

typedef __bf16 bf16x8 __attribute__((ext_vector_type(8)));
typedef float f32x4 __attribute__((ext_vector_type(4)));
typedef unsigned short ushort_t;

__device__ __forceinline__ unsigned short f2bf(float f) {
  unsigned int u = __float_as_uint(f);
  u += 0x7FFF + ((u >> 16) & 1);  // round-to-nearest-even
  return (unsigned short)(u >> 16);
}

__device__ __forceinline__ float era_f(float x) {
  // gelu_tanh(x) + GAMMA * softplus(x)
  float x3 = x * x * x;
  float inner = 0.7978845608028654f * (x + 0.044715f * x3);
  float e = __expf(2.0f * inner);
  float th = 1.0f - 2.0f / (e + 1.0f);       // tanh(inner), inf-safe
  float gelu = 0.5f * x * (1.0f + th);
  float sp = fmaxf(x, 0.0f) + __logf(1.0f + __expf(-fabsf(x)));
  return gelu + GAMMA * sp;
}

// ---------------- prep kernels ----------------

__global__ void convert_x(const float* __restrict__ in, ushort_t* __restrict__ out, int n) {
  int i = (blockIdx.x * 256 + threadIdx.x) * 4;
  if (i >= n) return;
  float4 v = *(const float4*)(in + i);
  out[i + 0] = f2bf(v.x);
  out[i + 1] = f2bf(v.y);
  out[i + 2] = f2bf(v.z);
  out[i + 3] = f2bf(v.w);
}

// in: fp32 [K][N] row-major  ->  out: bf16 [N][K]
__global__ void transpose_w(const float* __restrict__ in, ushort_t* __restrict__ out,
                            int K, int N) {
  __shared__ float tile[32][33];
  int k0 = blockIdx.y * 32, n0 = blockIdx.x * 32;
  int tr = threadIdx.x >> 5, tc = threadIdx.x & 31;
#pragma unroll
  for (int i = 0; i < 32; i += 8)
    tile[tr + i][tc] = in[(size_t)(k0 + tr + i) * N + n0 + tc];
  __syncthreads();
#pragma unroll
  for (int i = 0; i < 32; i += 8)
    out[(size_t)(n0 + tr + i) * K + k0 + tc] = f2bf(tile[tc][tr + i]);
}

// Wup fp32 [16][F] -> bf16 [F][32], k>=16 zero-padded
__global__ void pad_small(const float* __restrict__ in, ushort_t* __restrict__ out, int F) {
  int idx = blockIdx.x * 256 + threadIdx.x;  // F*32 total
  int f = idx >> 5, k = idx & 31;
  float v = (k < 16) ? in[(size_t)k * F + f] : 0.0f;
  out[idx] = f2bf(v);
}

// xd = SCALING * (x @ Wdn + bdn), stored bf16 [M][32] zero-padded; both g and u branches
__global__ void lora_down(const float* __restrict__ x,
                          const float* __restrict__ Wgd, const float* __restrict__ bgd,
                          const float* __restrict__ Wud, const float* __restrict__ bud,
                          ushort_t* __restrict__ xdg, ushort_t* __restrict__ xdu) {
  int row = blockIdx.x * 8 + (threadIdx.x >> 5);
  int c = threadIdx.x & 31;
  bool isG = (c < 16);
  int col = c & 15;
  const float* W = isG ? Wgd : Wud;
  const float* xr = x + (size_t)row * D_DIM;
  float acc = 0.0f;
  for (int k = 0; k < D_DIM; ++k)
    acc = fmaf(xr[k], W[k * 16 + col], acc);
  float b = isG ? bgd[col] : bud[col];
  ushort_t v = f2bf(SCALING * (acc + b));
  ushort_t* dst = isG ? xdg : xdu;
  dst[row * 32 + col] = v;
  dst[row * 32 + 16 + col] = 0;  // zero pad lanes k=16..31
}

// ---------------- GEMM helpers ----------------

__device__ __forceinline__ void stage_tile(ushort_t* dst, const ushort_t* src, int ldK) {
  int t = threadIdx.x;
#pragma unroll
  for (int p = 0; p < 2; ++p) {
    int idx = t + p * 256;
    int row = idx >> 2;   // 0..127
    int ch = idx & 3;     // 16B chunk within 64B row
    uint4 v = *(const uint4*)(src + (size_t)row * ldK + ch * 8);
    *(uint4*)(dst + row * LDS_PITCH + ch * 8) = v;
  }
}

__device__ __forceinline__ bf16x8 frag_ld(const ushort_t* lds, int row, int q) {
  union { uint4 u; bf16x8 v; } un;
  un.u = *(const uint4*)(lds + row * LDS_PITCH + q * 8);
  return un.v;
}

// ---------------- fused gate+up GEMM ----------------
// h_g = x@Wg + bg + xdg_s@Wgu + s*bgu ;  h_u analogous ;  t = ERA(h_g)*h_u (bf16)
__global__ __launch_bounds__(256) void gemm_gateup(
    const ushort_t* __restrict__ xbf, const ushort_t* __restrict__ Wgt,
    const ushort_t* __restrict__ Wut, const ushort_t* __restrict__ Wgup,
    const ushort_t* __restrict__ Wuup, const ushort_t* __restrict__ xdg,
    const ushort_t* __restrict__ xdu,
    const float* __restrict__ bg, const float* __restrict__ bgu,
    const float* __restrict__ bu, const float* __restrict__ buu,
    ushort_t* __restrict__ tout) {
  __shared__ ushort_t xs[128 * LDS_PITCH];
  __shared__ ushort_t wgs[128 * LDS_PITCH];
  __shared__ ushort_t wus[128 * LDS_PITCH];
  const int f0 = blockIdx.x * 128;
  const int m0 = blockIdx.y * 128;
  const int w = threadIdx.x >> 6, lane = threadIdx.x & 63;
  const int wm = w >> 1, wn = w & 1;
  const int ml = lane & 15, q = lane >> 4;

  const f32x4 zero4 = {0.f, 0.f, 0.f, 0.f};
  f32x4 accg[4][4], accu[4][4];
#pragma unroll
  for (int i = 0; i < 4; ++i)
#pragma unroll
    for (int j = 0; j < 4; ++j) { accg[i][j] = zero4; accu[i][j] = zero4; }

  const ushort_t* xsrc = xbf + (size_t)m0 * D_DIM;
  const ushort_t* gsrc = Wgt + (size_t)f0 * D_DIM;
  const ushort_t* usrc = Wut + (size_t)f0 * D_DIM;

  for (int kt = 0; kt < D_DIM / 32; ++kt) {
    __syncthreads();
    stage_tile(xs, xsrc + kt * 32, D_DIM);
    stage_tile(wgs, gsrc + kt * 32, D_DIM);
    stage_tile(wus, usrc + kt * 32, D_DIM);
    __syncthreads();
    bf16x8 af[4], bgf[4], buf2[4];
#pragma unroll
    for (int i = 0; i < 4; ++i) {
      af[i]   = frag_ld(xs,  wm * 64 + i * 16 + ml, q);
      bgf[i]  = frag_ld(wgs, wn * 64 + i * 16 + ml, q);
      buf2[i] = frag_ld(wus, wn * 64 + i * 16 + ml, q);
    }
#pragma unroll
    for (int mi = 0; mi < 4; ++mi)
#pragma unroll
      for (int ni = 0; ni < 4; ++ni) {
        accg[mi][ni] = __builtin_amdgcn_mfma_f32_16x16x32_bf16(af[mi], bgf[ni], accg[mi][ni], 0, 0, 0);
        accu[mi][ni] = __builtin_amdgcn_mfma_f32_16x16x32_bf16(af[mi], buf2[ni], accu[mi][ni], 0, 0, 0);
      }
  }

  // LoRA gate step (K=32, upper 16 zero-padded)
  __syncthreads();
  stage_tile(xs, xdg + (size_t)m0 * 32, 32);
  stage_tile(wgs, Wgup + (size_t)f0 * 32, 32);
  __syncthreads();
  {
    bf16x8 af[4], bgf[4];
#pragma unroll
    for (int i = 0; i < 4; ++i) {
      af[i]  = frag_ld(xs,  wm * 64 + i * 16 + ml, q);
      bgf[i] = frag_ld(wgs, wn * 64 + i * 16 + ml, q);
    }
#pragma unroll
    for (int mi = 0; mi < 4; ++mi)
#pragma unroll
      for (int ni = 0; ni < 4; ++ni)
        accg[mi][ni] = __builtin_amdgcn_mfma_f32_16x16x32_bf16(af[mi], bgf[ni], accg[mi][ni], 0, 0, 0);
  }
  // LoRA up step
  __syncthreads();
  stage_tile(xs, xdu + (size_t)m0 * 32, 32);
  stage_tile(wus, Wuup + (size_t)f0 * 32, 32);
  __syncthreads();
  {
    bf16x8 af[4], buf2[4];
#pragma unroll
    for (int i = 0; i < 4; ++i) {
      af[i]   = frag_ld(xs,  wm * 64 + i * 16 + ml, q);
      buf2[i] = frag_ld(wus, wn * 64 + i * 16 + ml, q);
    }
#pragma unroll
    for (int mi = 0; mi < 4; ++mi)
#pragma unroll
      for (int ni = 0; ni < 4; ++ni)
        accu[mi][ni] = __builtin_amdgcn_mfma_f32_16x16x32_bf16(af[mi], buf2[ni], accu[mi][ni], 0, 0, 0);
  }

  // epilogue: t = ERA(h_g) * h_u -> bf16
#pragma unroll
  for (int ni = 0; ni < 4; ++ni) {
    int col = f0 + wn * 64 + ni * 16 + ml;
    float cbg = bg[col] + SCALING * bgu[col];
    float cbu = bu[col] + SCALING * buu[col];
#pragma unroll
    for (int mi = 0; mi < 4; ++mi) {
      int row0 = m0 + wm * 64 + mi * 16 + q * 4;
#pragma unroll
      for (int r = 0; r < 4; ++r) {
        float hg = accg[mi][ni][r] + cbg;
        float hu = accu[mi][ni][r] + cbu;
        tout[(size_t)(row0 + r) * F_DIM + col] = f2bf(era_f(hg) * hu);
      }
    }
  }
}

// ---------------- down GEMM: out = t @ Wd + bd (fp32 out) ----------------
__global__ __launch_bounds__(256) void gemm_down(
    const ushort_t* __restrict__ tin, const ushort_t* __restrict__ Wdt,
    const float* __restrict__ bd, float* __restrict__ out) {
  __shared__ ushort_t as_[128 * LDS_PITCH];
  __shared__ ushort_t bs_[128 * LDS_PITCH];
  const int n0 = blockIdx.x * 128;
  const int m0 = blockIdx.y * 128;
  const int w = threadIdx.x >> 6, lane = threadIdx.x & 63;
  const int wm = w >> 1, wn = w & 1;
  const int ml = lane & 15, q = lane >> 4;

  const f32x4 zero4 = {0.f, 0.f, 0.f, 0.f};
  f32x4 acc[4][4];
#pragma unroll
  for (int i = 0; i < 4; ++i)
#pragma unroll
    for (int j = 0; j < 4; ++j) acc[i][j] = zero4;

  const ushort_t* asrc = tin + (size_t)m0 * F_DIM;
  const ushort_t* bsrc = Wdt + (size_t)n0 * F_DIM;

  for (int kt = 0; kt < F_DIM / 32; ++kt) {
    __syncthreads();
    stage_tile(as_, asrc + kt * 32, F_DIM);
    stage_tile(bs_, bsrc + kt * 32, F_DIM);
    __syncthreads();
    bf16x8 af[4], bf_[4];
#pragma unroll
    for (int i = 0; i < 4; ++i) {
      af[i]  = frag_ld(as_, wm * 64 + i * 16 + ml, q);
      bf_[i] = frag_ld(bs_, wn * 64 + i * 16 + ml, q);
    }
#pragma unroll
    for (int mi = 0; mi < 4; ++mi)
#pragma unroll
      for (int ni = 0; ni < 4; ++ni)
        acc[mi][ni] = __builtin_amdgcn_mfma_f32_16x16x32_bf16(af[mi], bf_[ni], acc[mi][ni], 0, 0, 0);
  }

#pragma unroll
  for (int ni = 0; ni < 4; ++ni) {
    int col = n0 + wn * 64 + ni * 16 + ml;
    float b = bd[col];
#pragma unroll
    for (int mi = 0; mi < 4; ++mi) {
      int row0 = m0 + wm * 64 + mi * 16 + q * 4;
#pragma unroll
      for (int r = 0; r < 4; ++r)
        out[(size_t)(row0 + r) * D_DIM + col] = acc[mi][ni][r] + b;
    }
  }
}

// ---------------- launcher ----------------

extern "C" void kernel_launch(void* const* d_in, const int* in_sizes, int n_in,
                              void* d_out, int out_size, void* d_ws, size_t ws_size,
                              hipStream_t stream) {
  const float* x   = (const float*)d_in[0];
  const float* Wg  = (const float*)d_in[1];
  const float* bg  = (const float*)d_in[2];
  const float* Wgd = (const float*)d_in[3];
  const float* bgd = (const float*)d_in[4];
  const float* Wgu = (const float*)d_in[5];
  const float* bgu = (const float*)d_in[6];
  const float* Wu  = (const float*)d_in[7];
  const float* bu  = (const float*)d_in[8];
  const float* Wud = (const float*)d_in[9];
  const float* bud = (const float*)d_in[10];
  const float* Wuu = (const float*)d_in[11];
  const float* buu = (const float*)d_in[12];
  const float* Wd  = (const float*)d_in[13];
  const float* bd  = (const float*)d_in[14];
  float* out = (float*)d_out;

  char* ws = (char*)d_ws;
  size_t off = 0;
  auto alloc = [&](size_t bytes) {
    char* p = ws + off;
    off += (bytes + 255) & ~(size_t)255;
    return p;
  };
  ushort_t* xbf  = (ushort_t*)alloc((size_t)M_DIM * D_DIM * 2);
  ushort_t* Wgt  = (ushort_t*)alloc((size_t)F_DIM * D_DIM * 2);
  ushort_t* Wut  = (ushort_t*)alloc((size_t)F_DIM * D_DIM * 2);
  ushort_t* Wdt  = (ushort_t*)alloc((size_t)D_DIM * F_DIM * 2);
  ushort_t* Wgup = (ushort_t*)alloc((size_t)F_DIM * 32 * 2);
  ushort_t* Wuup = (ushort_t*)alloc((size_t)F_DIM * 32 * 2);
  ushort_t* xdg  = (ushort_t*)alloc((size_t)M_DIM * 32 * 2);
  ushort_t* xdu  = (ushort_t*)alloc((size_t)M_DIM * 32 * 2);
  ushort_t* tbuf = (ushort_t*)alloc((size_t)M_DIM * F_DIM * 2);

  convert_x<<<(M_DIM * D_DIM / 4 + 255) / 256, 256, 0, stream>>>(x, xbf, M_DIM * D_DIM);
  transpose_w<<<dim3(F_DIM / 32, D_DIM / 32), 256, 0, stream>>>(Wg, Wgt, D_DIM, F_DIM);
  transpose_w<<<dim3(F_DIM / 32, D_DIM / 32), 256, 0, stream>>>(Wu, Wut, D_DIM, F_DIM);
  transpose_w<<<dim3(D_DIM / 32, F_DIM / 32), 256, 0, stream>>>(Wd, Wdt, F_DIM, D_DIM);
  pad_small<<<F_DIM * 32 / 256, 256, 0, stream>>>(Wgu, Wgup, F_DIM);
  pad_small<<<F_DIM * 32 / 256, 256, 0, stream>>>(Wuu, Wuup, F_DIM);
  lora_down<<<M_DIM / 8, 256, 0, stream>>>(x, Wgd, bgd, Wud, bud, xdg, xdu);
  gemm_gateup<<<dim3(F_DIM / 128, M_DIM / 128), 256, 0, stream>>>(
      xbf, Wgt, Wut, Wgup, Wuup, xdg, xdu, bg, bgu, bu, buu, tbuf);
  gemm_down<<<dim3(D_DIM / 128, M_DIM / 128), 256, 0, stream>>>(tbuf, Wdt, bd, out);
}